// Round 3
// baseline (217.590 us; speedup 1.0000x reference)
//
#include <hip/hip_runtime.h>
#include <hip/hip_bf16.h>

// SRA: B=16, C=64, H=W=64, heads=2, hd=32, N=4096, Nkv=1024, sr=2.
// Round 3: swapped-QK MFMA attention (8 waves/SIMD, exp2 softmax, b64 P-writes),
//          convkv split K/V across blocks (2x occupancy), coalesced bf16 stores.

#define B_ 16
#define C_ 64
#define N_ 4096
#define NKV_ 1024

typedef __bf16 bf16x8 __attribute__((ext_vector_type(8)));
typedef __bf16 bf16x4 __attribute__((ext_vector_type(4)));
typedef float f32x4 __attribute__((ext_vector_type(4)));

// ---------------- 1x1 conv fp32->fp32 (proj): Y[b,co,n] = sum_ci W[co,ci]*X[b,ci,n]
__global__ __launch_bounds__(256) void conv1x1_k(const float* __restrict__ X,
                                                 const float* __restrict__ W,
                                                 float* __restrict__ Y) {
    __shared__ float xs[64][132];
    __shared__ float ws[64][65];
    const int b = blockIdx.x;
    const int n0 = blockIdx.y * 128;
    const int t = threadIdx.x;

    for (int idx = t; idx < 64 * 64; idx += 256) ws[idx >> 6][idx & 63] = W[idx];
    const float* Xb = X + (size_t)b * C_ * N_ + n0;
    for (int idx = t; idx < 64 * 128; idx += 256) {
        int ci = idx >> 7, n = idx & 127;
        xs[ci][n] = Xb[ci * N_ + n];
    }
    __syncthreads();

    const int co0 = (t >> 4) * 4;
    const int nn0 = (t & 15) * 8;
    float acc[4][8];
#pragma unroll
    for (int k = 0; k < 4; ++k)
#pragma unroll
        for (int j = 0; j < 8; ++j) acc[k][j] = 0.f;

    for (int ci = 0; ci < 64; ++ci) {
        float w0 = ws[co0 + 0][ci], w1 = ws[co0 + 1][ci];
        float w2 = ws[co0 + 2][ci], w3 = ws[co0 + 3][ci];
        float4 xa = *(const float4*)&xs[ci][nn0];
        float4 xb = *(const float4*)&xs[ci][nn0 + 4];
        float xv[8] = {xa.x, xa.y, xa.z, xa.w, xb.x, xb.y, xb.z, xb.w};
#pragma unroll
        for (int j = 0; j < 8; ++j) {
            acc[0][j] = fmaf(w0, xv[j], acc[0][j]);
            acc[1][j] = fmaf(w1, xv[j], acc[1][j]);
            acc[2][j] = fmaf(w2, xv[j], acc[2][j]);
            acc[3][j] = fmaf(w3, xv[j], acc[3][j]);
        }
    }
    float* Yb = Y + (size_t)b * C_ * N_ + n0;
#pragma unroll
    for (int k = 0; k < 4; ++k) {
        float4 o0 = {acc[k][0], acc[k][1], acc[k][2], acc[k][3]};
        float4 o1 = {acc[k][4], acc[k][5], acc[k][6], acc[k][7]};
        *(float4*)&Yb[(co0 + k) * N_ + nn0] = o0;
        *(float4*)&Yb[(co0 + k) * N_ + nn0 + 4] = o1;
    }
}

// ---------------- Q conv: fp32 GEMM, writes bf16 Qt[bh][n][32d], scale*log2e folded.
// Mapping: co across lanes -> coalesced [n][d] bf16x4 stores.
__global__ __launch_bounds__(256) void qconv_k(const float* __restrict__ X,
                                               const float* __restrict__ W,
                                               __bf16* __restrict__ Qt) {
    __shared__ float xs[64][132];
    __shared__ float ws[64][65];
    const int b = blockIdx.x;
    const int n0 = blockIdx.y * 128;
    const int t = threadIdx.x;
    const float scale = 0.25503487572f;   // log2(e)/sqrt(32)

    for (int idx = t; idx < 64 * 64; idx += 256) ws[idx >> 6][idx & 63] = W[idx];
    const float* Xb = X + (size_t)b * C_ * N_ + n0;
    for (int idx = t; idx < 64 * 128; idx += 256) {
        int ci = idx >> 7, n = idx & 127;
        xs[ci][n] = Xb[ci * N_ + n];
    }
    __syncthreads();

    const int co0 = (t & 15) * 4;    // lanes 0-15 cover all 64 co
    const int nn0 = (t >> 4) * 8;    // broadcast xs reads
    float acc[4][8];
#pragma unroll
    for (int k = 0; k < 4; ++k)
#pragma unroll
        for (int j = 0; j < 8; ++j) acc[k][j] = 0.f;

    for (int ci = 0; ci < 64; ++ci) {
        float w0 = ws[co0 + 0][ci], w1 = ws[co0 + 1][ci];
        float w2 = ws[co0 + 2][ci], w3 = ws[co0 + 3][ci];
        float4 xa = *(const float4*)&xs[ci][nn0];
        float4 xb = *(const float4*)&xs[ci][nn0 + 4];
        float xv[8] = {xa.x, xa.y, xa.z, xa.w, xb.x, xb.y, xb.z, xb.w};
#pragma unroll
        for (int j = 0; j < 8; ++j) {
            acc[0][j] = fmaf(w0, xv[j], acc[0][j]);
            acc[1][j] = fmaf(w1, xv[j], acc[1][j]);
            acc[2][j] = fmaf(w2, xv[j], acc[2][j]);
            acc[3][j] = fmaf(w3, xv[j], acc[3][j]);
        }
    }
    const int h = co0 >> 5, d0 = co0 & 31;
    __bf16* Qb = Qt + (size_t)(b * 2 + h) * N_ * 32;
#pragma unroll
    for (int j = 0; j < 8; ++j) {
        bf16x4 v = {(__bf16)(acc[0][j] * scale), (__bf16)(acc[1][j] * scale),
                    (__bf16)(acc[2][j] * scale), (__bf16)(acc[3][j] * scale)};
        *(bf16x4*)&Qb[(size_t)(n0 + nn0 + j) * 32 + d0] = v;
    }
}

// ---------------- 2x2 stride-2 conv; blockIdx.z selects K (->Kt[m][32d]) or V (->Vh[d][m]).
__global__ __launch_bounds__(256) void convkv_k(const float* __restrict__ X,
                                                const float* __restrict__ Wk,
                                                const float* __restrict__ Wv,
                                                __bf16* __restrict__ Kt,
                                                __bf16* __restrict__ Vh) {
    __shared__ float xs[64][64];
    __shared__ float ws[64][65];
    const int b = blockIdx.x;
    const int m0 = blockIdx.y * 64;
    const int kv = blockIdx.z;          // 0 = K, 1 = V
    const int i0 = m0 >> 5;
    const int t = threadIdx.x;
    // V-blocks: m across lanes (coalesced [d][m] stores). K-blocks: co across lanes ([m][d] stores).
    const int co0 = kv ? (t >> 4) * 4 : (t & 15) * 4;
    const int mm0 = kv ? (t & 15) * 4 : (t >> 4) * 4;
    const float* Wsel = kv ? Wv : Wk;

    float acc[4][4];
#pragma unroll
    for (int k = 0; k < 4; ++k)
#pragma unroll
        for (int m = 0; m < 4; ++m) acc[k][m] = 0.f;

    const float* Xb = X + (size_t)b * C_ * N_;

    for (int ch = 0; ch < 4; ++ch) {
        for (int idx = t; idx < 4096; idx += 256) {
            int co = idx >> 6, rl = idx & 63;
            ws[co][rl] = Wsel[co * 256 + ch * 64 + rl];
        }
        for (int idx = t; idx < 4096; idx += 256) {
            int rl = idx >> 6, ml = idx & 63;
            int ci = ch * 16 + (rl >> 2);
            int di = (rl >> 1) & 1, dj = rl & 1;
            int i = i0 + (ml >> 5), j = ml & 31;
            xs[rl][ml] = Xb[ci * N_ + (2 * i + di) * 64 + (2 * j + dj)];
        }
        __syncthreads();
        for (int rl = 0; rl < 64; ++rl) {
            float4 xv4 = *(const float4*)&xs[rl][mm0];
            float xa[4] = {xv4.x, xv4.y, xv4.z, xv4.w};
#pragma unroll
            for (int k = 0; k < 4; ++k) {
                float wv = ws[co0 + k][rl];
#pragma unroll
                for (int m = 0; m < 4; ++m) acc[k][m] = fmaf(wv, xa[m], acc[k][m]);
            }
        }
        __syncthreads();
    }
    const int h = co0 >> 5, d0 = co0 & 31;
    if (kv) {
        __bf16* Vb = Vh + (size_t)(b * 2 + h) * 32 * NKV_;
#pragma unroll
        for (int k = 0; k < 4; ++k) {
            bf16x4 vv = {(__bf16)acc[k][0], (__bf16)acc[k][1],
                         (__bf16)acc[k][2], (__bf16)acc[k][3]};
            *(bf16x4*)&Vb[(size_t)(d0 + k) * NKV_ + m0 + mm0] = vv;
        }
    } else {
        __bf16* Kb = Kt + (size_t)(b * 2 + h) * NKV_ * 32;
#pragma unroll
        for (int mq = 0; mq < 4; ++mq) {
            bf16x4 kvv = {(__bf16)acc[0][mq], (__bf16)acc[1][mq],
                          (__bf16)acc[2][mq], (__bf16)acc[3][mq]};
            *(bf16x4*)&Kb[(size_t)(m0 + mm0 + mq) * 32 + d0] = kvv;
        }
    }
}

// ---------------- MFMA flash attention, swapped QK, 16 q-rows per wave.
// s = mfma(K,Q) -> D[m][n]: lane holds P[n=lr][m=4lg+r] -> contiguous b64 P writes.
__global__ __launch_bounds__(256, 8) void attn_mfma(const __bf16* __restrict__ Qt,
                                                    const __bf16* __restrict__ Kt,
                                                    const __bf16* __restrict__ Vh,
                                                    float* __restrict__ O) {
    __shared__ __attribute__((aligned(16))) __bf16 Pls[4][16][40];  // [wave][n][m+pad], 80B rows
    const int bh = blockIdx.x;
    const int w = threadIdx.x >> 6;
    const int l = threadIdx.x & 63;
    const int lr = l & 15, lg = l >> 4;
    const int nb = blockIdx.y * 64 + w * 16;

    const __bf16* Qb = Qt + (size_t)bh * N_ * 32;
    const __bf16* Kb = Kt + (size_t)bh * NKV_ * 32;
    const __bf16* Vb = Vh + (size_t)bh * 32 * NKV_;

    // A/B fragment: outer = lane&15, k = 8*(lane>>4)+j (contiguous 16B)
    const bf16x8 qf = *(const bf16x8*)&Qb[(size_t)(nb + lr) * 32 + 8 * lg];
    const __bf16* Krow = Kb + (size_t)lr * 32 + 8 * lg;
    const __bf16* V0 = Vb + (size_t)lr * NKV_ + 8 * lg;
    const __bf16* V1 = Vb + (size_t)(16 + lr) * NKV_ + 8 * lg;

    f32x4 oacc0 = {0.f, 0.f, 0.f, 0.f}, oacc1 = {0.f, 0.f, 0.f, 0.f};
    float lsum = 0.f;

    for (int mb = 0; mb < NKV_; mb += 32) {
        bf16x8 kf0 = *(const bf16x8*)&Krow[(size_t)mb * 32];
        bf16x8 kf1 = *(const bf16x8*)&Krow[(size_t)(mb + 16) * 32];
        f32x4 s0 = __builtin_amdgcn_mfma_f32_16x16x32_bf16(kf0, qf, (f32x4){0.f,0.f,0.f,0.f}, 0, 0, 0);
        f32x4 s1 = __builtin_amdgcn_mfma_f32_16x16x32_bf16(kf1, qf, (f32x4){0.f,0.f,0.f,0.f}, 0, 0, 0);
        float p0[4], p1[4];
#pragma unroll
        for (int r = 0; r < 4; ++r) {
            p0[r] = __builtin_amdgcn_exp2f(s0[r]);   // s already in log2 domain
            p1[r] = __builtin_amdgcn_exp2f(s1[r]);
        }
        lsum += ((p0[0] + p0[1]) + (p0[2] + p0[3])) + ((p1[0] + p1[1]) + (p1[2] + p1[3]));
        bf16x4 w0 = {(__bf16)p0[0], (__bf16)p0[1], (__bf16)p0[2], (__bf16)p0[3]};
        bf16x4 w1 = {(__bf16)p1[0], (__bf16)p1[1], (__bf16)p1[2], (__bf16)p1[3]};
        *(bf16x4*)&Pls[w][lr][4 * lg] = w0;            // m = 4lg..4lg+3
        *(bf16x4*)&Pls[w][lr][16 + 4 * lg] = w1;       // m = 16+4lg..
        bf16x8 af = *(const bf16x8*)&Pls[w][lr][8 * lg];   // P[n=lr][m=8lg..8lg+7]
        bf16x8 vf0 = *(const bf16x8*)&V0[mb];
        bf16x8 vf1 = *(const bf16x8*)&V1[mb];
        oacc0 = __builtin_amdgcn_mfma_f32_16x16x32_bf16(af, vf0, oacc0, 0, 0, 0);
        oacc1 = __builtin_amdgcn_mfma_f32_16x16x32_bf16(af, vf1, oacc1, 0, 0, 0);
    }

    // complete row sums (row n=lr): combine the 4 lg-groups
    lsum += __shfl_xor(lsum, 16, 64);
    lsum += __shfl_xor(lsum, 32, 64);
    float inv[4];
#pragma unroll
    for (int r = 0; r < 4; ++r) inv[r] = 1.0f / __shfl(lsum, 4 * lg + r, 64);

    const int b = bh >> 1, h = bh & 1;
    // PV D layout: row n = 4lg+r, col d = lr(+16)
    float4 o0 = {oacc0[0] * inv[0], oacc0[1] * inv[1], oacc0[2] * inv[2], oacc0[3] * inv[3]};
    float4 o1 = {oacc1[0] * inv[0], oacc1[1] * inv[1], oacc1[2] * inv[2], oacc1[3] * inv[3]};
    const size_t c0 = (size_t)b * 64 + h * 32 + lr;
    *(float4*)&O[c0 * N_ + nb + 4 * lg] = o0;
    *(float4*)&O[(c0 + 16) * N_ + nb + 4 * lg] = o1;
}

extern "C" void kernel_launch(void* const* d_in, const int* in_sizes, int n_in,
                              void* d_out, int out_size, void* d_ws, size_t ws_size,
                              hipStream_t stream) {
    const float* x     = (const float*)d_in[0];
    const float* wq    = (const float*)d_in[1];
    const float* wk    = (const float*)d_in[2];
    const float* wv    = (const float*)d_in[3];
    const float* wproj = (const float*)d_in[4];
    float* out = (float*)d_out;

    char* ws = (char*)d_ws;
    __bf16* Qt = (__bf16*)ws;                                   // 8.39 MB
    __bf16* Kt = (__bf16*)(ws + 8388608);                       // 2.10 MB
    __bf16* Vh = (__bf16*)(ws + 8388608 + 2097152);             // 2.10 MB
    float*  O  = (float*)(ws + 8388608 + 2097152 + 2097152);    // 16.78 MB

    qconv_k <<<dim3(B_, N_ / 128), 256, 0, stream>>>(x, wq, Qt);
    convkv_k<<<dim3(B_, NKV_ / 64, 2), 256, 0, stream>>>(x, wk, wv, Kt, Vh);
    attn_mfma<<<dim3(B_ * 2, N_ / 64), 256, 0, stream>>>(Qt, Kt, Vh, O);
    conv1x1_k<<<dim3(B_, N_ / 128), 256, 0, stream>>>(O, wproj, out);
}

// Round 4
// 177.790 us; speedup vs baseline: 1.2239x; 1.2239x over previous
//
#include <hip/hip_runtime.h>
#include <hip/hip_bf16.h>

// SRA: B=16, C=64, H=W=64, heads=2, hd=32, N=4096, Nkv=1024, sr=2.
// Round 4: attn = swapped-QK MFMA, 32 q-rows/wave, explicit K/V prefetch,
//          exp2 softmax, b64 P-writes, setprio. Convs unchanged from round 3.

#define B_ 16
#define C_ 64
#define N_ 4096
#define NKV_ 1024

typedef __bf16 bf16x8 __attribute__((ext_vector_type(8)));
typedef __bf16 bf16x4 __attribute__((ext_vector_type(4)));
typedef float f32x4 __attribute__((ext_vector_type(4)));

// ---------------- 1x1 conv fp32->fp32 (proj): Y[b,co,n] = sum_ci W[co,ci]*X[b,ci,n]
__global__ __launch_bounds__(256) void conv1x1_k(const float* __restrict__ X,
                                                 const float* __restrict__ W,
                                                 float* __restrict__ Y) {
    __shared__ float xs[64][132];
    __shared__ float ws[64][65];
    const int b = blockIdx.x;
    const int n0 = blockIdx.y * 128;
    const int t = threadIdx.x;

    for (int idx = t; idx < 64 * 64; idx += 256) ws[idx >> 6][idx & 63] = W[idx];
    const float* Xb = X + (size_t)b * C_ * N_ + n0;
    for (int idx = t; idx < 64 * 128; idx += 256) {
        int ci = idx >> 7, n = idx & 127;
        xs[ci][n] = Xb[ci * N_ + n];
    }
    __syncthreads();

    const int co0 = (t >> 4) * 4;
    const int nn0 = (t & 15) * 8;
    float acc[4][8];
#pragma unroll
    for (int k = 0; k < 4; ++k)
#pragma unroll
        for (int j = 0; j < 8; ++j) acc[k][j] = 0.f;

    for (int ci = 0; ci < 64; ++ci) {
        float w0 = ws[co0 + 0][ci], w1 = ws[co0 + 1][ci];
        float w2 = ws[co0 + 2][ci], w3 = ws[co0 + 3][ci];
        float4 xa = *(const float4*)&xs[ci][nn0];
        float4 xb = *(const float4*)&xs[ci][nn0 + 4];
        float xv[8] = {xa.x, xa.y, xa.z, xa.w, xb.x, xb.y, xb.z, xb.w};
#pragma unroll
        for (int j = 0; j < 8; ++j) {
            acc[0][j] = fmaf(w0, xv[j], acc[0][j]);
            acc[1][j] = fmaf(w1, xv[j], acc[1][j]);
            acc[2][j] = fmaf(w2, xv[j], acc[2][j]);
            acc[3][j] = fmaf(w3, xv[j], acc[3][j]);
        }
    }
    float* Yb = Y + (size_t)b * C_ * N_ + n0;
#pragma unroll
    for (int k = 0; k < 4; ++k) {
        float4 o0 = {acc[k][0], acc[k][1], acc[k][2], acc[k][3]};
        float4 o1 = {acc[k][4], acc[k][5], acc[k][6], acc[k][7]};
        *(float4*)&Yb[(co0 + k) * N_ + nn0] = o0;
        *(float4*)&Yb[(co0 + k) * N_ + nn0 + 4] = o1;
    }
}

// ---------------- Q conv: fp32 GEMM, writes bf16 Qt[bh][n][32d], scale*log2e folded.
__global__ __launch_bounds__(256) void qconv_k(const float* __restrict__ X,
                                               const float* __restrict__ W,
                                               __bf16* __restrict__ Qt) {
    __shared__ float xs[64][132];
    __shared__ float ws[64][65];
    const int b = blockIdx.x;
    const int n0 = blockIdx.y * 128;
    const int t = threadIdx.x;
    const float scale = 0.25503487572f;   // log2(e)/sqrt(32)

    for (int idx = t; idx < 64 * 64; idx += 256) ws[idx >> 6][idx & 63] = W[idx];
    const float* Xb = X + (size_t)b * C_ * N_ + n0;
    for (int idx = t; idx < 64 * 128; idx += 256) {
        int ci = idx >> 7, n = idx & 127;
        xs[ci][n] = Xb[ci * N_ + n];
    }
    __syncthreads();

    const int co0 = (t & 15) * 4;
    const int nn0 = (t >> 4) * 8;
    float acc[4][8];
#pragma unroll
    for (int k = 0; k < 4; ++k)
#pragma unroll
        for (int j = 0; j < 8; ++j) acc[k][j] = 0.f;

    for (int ci = 0; ci < 64; ++ci) {
        float w0 = ws[co0 + 0][ci], w1 = ws[co0 + 1][ci];
        float w2 = ws[co0 + 2][ci], w3 = ws[co0 + 3][ci];
        float4 xa = *(const float4*)&xs[ci][nn0];
        float4 xb = *(const float4*)&xs[ci][nn0 + 4];
        float xv[8] = {xa.x, xa.y, xa.z, xa.w, xb.x, xb.y, xb.z, xb.w};
#pragma unroll
        for (int j = 0; j < 8; ++j) {
            acc[0][j] = fmaf(w0, xv[j], acc[0][j]);
            acc[1][j] = fmaf(w1, xv[j], acc[1][j]);
            acc[2][j] = fmaf(w2, xv[j], acc[2][j]);
            acc[3][j] = fmaf(w3, xv[j], acc[3][j]);
        }
    }
    const int h = co0 >> 5, d0 = co0 & 31;
    __bf16* Qb = Qt + (size_t)(b * 2 + h) * N_ * 32;
#pragma unroll
    for (int j = 0; j < 8; ++j) {
        bf16x4 v = {(__bf16)(acc[0][j] * scale), (__bf16)(acc[1][j] * scale),
                    (__bf16)(acc[2][j] * scale), (__bf16)(acc[3][j] * scale)};
        *(bf16x4*)&Qb[(size_t)(n0 + nn0 + j) * 32 + d0] = v;
    }
}

// ---------------- 2x2 stride-2 conv; blockIdx.z selects K (->Kt[m][32d]) or V (->Vh[d][m]).
__global__ __launch_bounds__(256) void convkv_k(const float* __restrict__ X,
                                                const float* __restrict__ Wk,
                                                const float* __restrict__ Wv,
                                                __bf16* __restrict__ Kt,
                                                __bf16* __restrict__ Vh) {
    __shared__ float xs[64][64];
    __shared__ float ws[64][65];
    const int b = blockIdx.x;
    const int m0 = blockIdx.y * 64;
    const int kv = blockIdx.z;
    const int i0 = m0 >> 5;
    const int t = threadIdx.x;
    const int co0 = kv ? (t >> 4) * 4 : (t & 15) * 4;
    const int mm0 = kv ? (t & 15) * 4 : (t >> 4) * 4;
    const float* Wsel = kv ? Wv : Wk;

    float acc[4][4];
#pragma unroll
    for (int k = 0; k < 4; ++k)
#pragma unroll
        for (int m = 0; m < 4; ++m) acc[k][m] = 0.f;

    const float* Xb = X + (size_t)b * C_ * N_;

    for (int ch = 0; ch < 4; ++ch) {
        for (int idx = t; idx < 4096; idx += 256) {
            int co = idx >> 6, rl = idx & 63;
            ws[co][rl] = Wsel[co * 256 + ch * 64 + rl];
        }
        for (int idx = t; idx < 4096; idx += 256) {
            int rl = idx >> 6, ml = idx & 63;
            int ci = ch * 16 + (rl >> 2);
            int di = (rl >> 1) & 1, dj = rl & 1;
            int i = i0 + (ml >> 5), j = ml & 31;
            xs[rl][ml] = Xb[ci * N_ + (2 * i + di) * 64 + (2 * j + dj)];
        }
        __syncthreads();
        for (int rl = 0; rl < 64; ++rl) {
            float4 xv4 = *(const float4*)&xs[rl][mm0];
            float xa[4] = {xv4.x, xv4.y, xv4.z, xv4.w};
#pragma unroll
            for (int k = 0; k < 4; ++k) {
                float wv = ws[co0 + k][rl];
#pragma unroll
                for (int m = 0; m < 4; ++m) acc[k][m] = fmaf(wv, xa[m], acc[k][m]);
            }
        }
        __syncthreads();
    }
    const int h = co0 >> 5, d0 = co0 & 31;
    if (kv) {
        __bf16* Vb = Vh + (size_t)(b * 2 + h) * 32 * NKV_;
#pragma unroll
        for (int k = 0; k < 4; ++k) {
            bf16x4 vv = {(__bf16)acc[k][0], (__bf16)acc[k][1],
                         (__bf16)acc[k][2], (__bf16)acc[k][3]};
            *(bf16x4*)&Vb[(size_t)(d0 + k) * NKV_ + m0 + mm0] = vv;
        }
    } else {
        __bf16* Kb = Kt + (size_t)(b * 2 + h) * NKV_ * 32;
#pragma unroll
        for (int mq = 0; mq < 4; ++mq) {
            bf16x4 kvv = {(__bf16)acc[0][mq], (__bf16)acc[1][mq],
                          (__bf16)acc[2][mq], (__bf16)acc[3][mq]};
            *(bf16x4*)&Kb[(size_t)(m0 + mm0 + mq) * 32 + d0] = kvv;
        }
    }
}

// ---------------- MFMA flash attention: swapped QK, 32 q-rows/wave, K/V prefetch.
// s = mfma(K,Q): lane(lr,lg) holds P[n=lr][m=4lg+r]; b64 P writes; b128 P reads.
__global__ __launch_bounds__(256, 4) void attn_mfma(const __bf16* __restrict__ Qt,
                                                    const __bf16* __restrict__ Kt,
                                                    const __bf16* __restrict__ Vh,
                                                    float* __restrict__ O) {
    __shared__ __attribute__((aligned(16))) __bf16 Pls[4][2][16][40];  // [wave][t][n][m+pad]
    const int bh = blockIdx.x;
    const int w = threadIdx.x >> 6;
    const int l = threadIdx.x & 63;
    const int lr = l & 15, lg = l >> 4;
    const int nb = blockIdx.y * 128 + w * 32;

    const __bf16* Qb = Qt + (size_t)bh * N_ * 32;
    const __bf16* Kb = Kt + (size_t)bh * NKV_ * 32;
    const __bf16* Vb = Vh + (size_t)bh * 32 * NKV_;

    // fragments: outer index = lane&15, k = 8*(lane>>4)+j (contiguous 16B)
    bf16x8 qf0 = *(const bf16x8*)&Qb[(size_t)(nb + lr) * 32 + 8 * lg];
    bf16x8 qf1 = *(const bf16x8*)&Qb[(size_t)(nb + 16 + lr) * 32 + 8 * lg];
    const __bf16* Krow = Kb + (size_t)lr * 32 + 8 * lg;
    const __bf16* V0 = Vb + (size_t)lr * NKV_ + 8 * lg;
    const __bf16* V1 = Vb + (size_t)(16 + lr) * NKV_ + 8 * lg;

    f32x4 oacc00 = {0,0,0,0}, oacc01 = {0,0,0,0}, oacc10 = {0,0,0,0}, oacc11 = {0,0,0,0};
    float lsum0 = 0.f, lsum1 = 0.f;

    // prime the pipeline
    bf16x8 kf0 = *(const bf16x8*)&Krow[0];
    bf16x8 kf1 = *(const bf16x8*)&Krow[16 * 32];
    bf16x8 vf0 = *(const bf16x8*)&V0[0];
    bf16x8 vf1 = *(const bf16x8*)&V1[0];

    for (int mb = 0; mb < NKV_; mb += 32) {
        const int mn = (mb + 32) & (NKV_ - 1);   // wrap: last-iter prefetch is harmless
        bf16x8 nk0 = *(const bf16x8*)&Krow[(size_t)mn * 32];
        bf16x8 nk1 = *(const bf16x8*)&Krow[(size_t)(mn + 16) * 32];
        bf16x8 nv0 = *(const bf16x8*)&V0[mn];
        bf16x8 nv1 = *(const bf16x8*)&V1[mn];

        __builtin_amdgcn_s_setprio(1);
        f32x4 s00 = __builtin_amdgcn_mfma_f32_16x16x32_bf16(kf0, qf0, (f32x4){0,0,0,0}, 0, 0, 0);
        f32x4 s10 = __builtin_amdgcn_mfma_f32_16x16x32_bf16(kf1, qf0, (f32x4){0,0,0,0}, 0, 0, 0);
        f32x4 s01 = __builtin_amdgcn_mfma_f32_16x16x32_bf16(kf0, qf1, (f32x4){0,0,0,0}, 0, 0, 0);
        f32x4 s11 = __builtin_amdgcn_mfma_f32_16x16x32_bf16(kf1, qf1, (f32x4){0,0,0,0}, 0, 0, 0);
        __builtin_amdgcn_s_setprio(0);

        float p00[4], p10[4], p01[4], p11[4];
#pragma unroll
        for (int r = 0; r < 4; ++r) {
            p00[r] = __builtin_amdgcn_exp2f(s00[r]);
            p10[r] = __builtin_amdgcn_exp2f(s10[r]);
            p01[r] = __builtin_amdgcn_exp2f(s01[r]);
            p11[r] = __builtin_amdgcn_exp2f(s11[r]);
        }
        lsum0 += ((p00[0] + p00[1]) + (p00[2] + p00[3])) + ((p10[0] + p10[1]) + (p10[2] + p10[3]));
        lsum1 += ((p01[0] + p01[1]) + (p01[2] + p01[3])) + ((p11[0] + p11[1]) + (p11[2] + p11[3]));

        bf16x4 w00 = {(__bf16)p00[0], (__bf16)p00[1], (__bf16)p00[2], (__bf16)p00[3]};
        bf16x4 w10 = {(__bf16)p10[0], (__bf16)p10[1], (__bf16)p10[2], (__bf16)p10[3]};
        bf16x4 w01 = {(__bf16)p01[0], (__bf16)p01[1], (__bf16)p01[2], (__bf16)p01[3]};
        bf16x4 w11 = {(__bf16)p11[0], (__bf16)p11[1], (__bf16)p11[2], (__bf16)p11[3]};
        *(bf16x4*)&Pls[w][0][lr][4 * lg] = w00;
        *(bf16x4*)&Pls[w][0][lr][16 + 4 * lg] = w10;
        *(bf16x4*)&Pls[w][1][lr][4 * lg] = w01;
        *(bf16x4*)&Pls[w][1][lr][16 + 4 * lg] = w11;

        bf16x8 af0 = *(const bf16x8*)&Pls[w][0][lr][8 * lg];
        bf16x8 af1 = *(const bf16x8*)&Pls[w][1][lr][8 * lg];

        __builtin_amdgcn_s_setprio(1);
        oacc00 = __builtin_amdgcn_mfma_f32_16x16x32_bf16(af0, vf0, oacc00, 0, 0, 0);
        oacc01 = __builtin_amdgcn_mfma_f32_16x16x32_bf16(af0, vf1, oacc01, 0, 0, 0);
        oacc10 = __builtin_amdgcn_mfma_f32_16x16x32_bf16(af1, vf0, oacc10, 0, 0, 0);
        oacc11 = __builtin_amdgcn_mfma_f32_16x16x32_bf16(af1, vf1, oacc11, 0, 0, 0);
        __builtin_amdgcn_s_setprio(0);

        kf0 = nk0; kf1 = nk1; vf0 = nv0; vf1 = nv1;
    }

    // complete row sums: combine 4 lg-groups (lanes lr, lr+16, lr+32, lr+48)
    lsum0 += __shfl_xor(lsum0, 16, 64);
    lsum0 += __shfl_xor(lsum0, 32, 64);
    lsum1 += __shfl_xor(lsum1, 16, 64);
    lsum1 += __shfl_xor(lsum1, 32, 64);
    float inv0[4], inv1[4];
#pragma unroll
    for (int r = 0; r < 4; ++r) {
        inv0[r] = 1.0f / __shfl(lsum0, 4 * lg + r, 64);
        inv1[r] = 1.0f / __shfl(lsum1, 4 * lg + r, 64);
    }

    const int b = bh >> 1, h = bh & 1;
    const size_t c0 = (size_t)b * 64 + h * 32 + lr;
    float4 o;
    o = (float4){oacc00[0]*inv0[0], oacc00[1]*inv0[1], oacc00[2]*inv0[2], oacc00[3]*inv0[3]};
    *(float4*)&O[c0 * N_ + nb + 4 * lg] = o;
    o = (float4){oacc01[0]*inv0[0], oacc01[1]*inv0[1], oacc01[2]*inv0[2], oacc01[3]*inv0[3]};
    *(float4*)&O[(c0 + 16) * N_ + nb + 4 * lg] = o;
    o = (float4){oacc10[0]*inv1[0], oacc10[1]*inv1[1], oacc10[2]*inv1[2], oacc10[3]*inv1[3]};
    *(float4*)&O[c0 * N_ + nb + 16 + 4 * lg] = o;
    o = (float4){oacc11[0]*inv1[0], oacc11[1]*inv1[1], oacc11[2]*inv1[2], oacc11[3]*inv1[3]};
    *(float4*)&O[(c0 + 16) * N_ + nb + 16 + 4 * lg] = o;
}

extern "C" void kernel_launch(void* const* d_in, const int* in_sizes, int n_in,
                              void* d_out, int out_size, void* d_ws, size_t ws_size,
                              hipStream_t stream) {
    const float* x     = (const float*)d_in[0];
    const float* wq    = (const float*)d_in[1];
    const float* wk    = (const float*)d_in[2];
    const float* wv    = (const float*)d_in[3];
    const float* wproj = (const float*)d_in[4];
    float* out = (float*)d_out;

    char* ws = (char*)d_ws;
    __bf16* Qt = (__bf16*)ws;                                   // 8.39 MB
    __bf16* Kt = (__bf16*)(ws + 8388608);                       // 2.10 MB
    __bf16* Vh = (__bf16*)(ws + 8388608 + 2097152);             // 2.10 MB
    float*  O  = (float*)(ws + 8388608 + 2097152 + 2097152);    // 16.78 MB

    qconv_k <<<dim3(B_, N_ / 128), 256, 0, stream>>>(x, wq, Qt);
    convkv_k<<<dim3(B_, NKV_ / 64, 2), 256, 0, stream>>>(x, wk, wv, Kt, Vh);
    attn_mfma<<<dim3(B_ * 2, N_ / 128), 256, 0, stream>>>(Qt, Kt, Vh, O);
    conv1x1_k<<<dim3(B_, N_ / 128), 256, 0, stream>>>(O, wproj, out);
}

// Round 5
// 163.594 us; speedup vs baseline: 1.3301x; 1.0868x over previous
//
#include <hip/hip_runtime.h>
#include <hip/hip_bf16.h>

// SRA: B=16, C=64, H=W=64, heads=2, hd=32, N=4096, Nkv=1024, sr=2.
// Round 5: all convs -> bf16 MFMA. Layouts co-designed:
//   qconv  -> Qt[b][n][64c] bf16 (scale*log2e folded)
//   kvconv -> Kt[b][m][64c], Vh[b][64c][m] bf16
//   attn   -> OT[b][n][64c] bf16 (PV operands swapped: D = mfma(V, P))
//   proj   -> reads OT fragments from global, writes fp32 out.

#define B_ 16
#define C_ 64
#define N_ 4096
#define NKV_ 1024

typedef __bf16 bf16x8 __attribute__((ext_vector_type(8)));
typedef __bf16 bf16x4 __attribute__((ext_vector_type(4)));
typedef float f32x4 __attribute__((ext_vector_type(4)));

// ---------------- Q conv (1x1) as MFMA GEMM: D = W(scaled) @ X  -> Qt[n][c]
// Block: 128 n, all 64 co. 4 waves x (2 nsub x 4 cot x 2 ks) MFMAs.
__global__ __launch_bounds__(256) void qconv_mfma(const float* __restrict__ X,
                                                  const float* __restrict__ W,
                                                  __bf16* __restrict__ Qt) {
    __shared__ __bf16 xls[128][72];   // [n][ci], 144B rows: 16B-aligned, 2-way banks
    const int b = blockIdx.x, n0 = blockIdx.y * 128, t = threadIdx.x;
    const int w = t >> 6, l = t & 63, lr = l & 15, lg = l >> 4;
    const float scale = 0.25503487572f;   // log2(e)/sqrt(32)

    const float* Xb = X + (size_t)b * C_ * N_ + n0;
    for (int idx = t; idx < 2048; idx += 256) {          // 64ci x 128n floats
        int ci = idx >> 5, n4 = (idx & 31) * 4;
        float4 v = *(const float4*)&Xb[ci * N_ + n4];
        xls[n4 + 0][ci] = (__bf16)v.x; xls[n4 + 1][ci] = (__bf16)v.y;
        xls[n4 + 2][ci] = (__bf16)v.z; xls[n4 + 3][ci] = (__bf16)v.w;
    }
    // A-frags: a[cot][ks] = W[cot*16+lr][ks*32 + 8lg + j] * scale
    bf16x8 a[4][2];
#pragma unroll
    for (int cot = 0; cot < 4; ++cot)
#pragma unroll
        for (int ks = 0; ks < 2; ++ks) {
            const float* wp = &W[(cot * 16 + lr) * 64 + ks * 32 + 8 * lg];
            float4 w0 = *(const float4*)wp;
            float4 w1 = *(const float4*)(wp + 4);
            a[cot][ks] = (bf16x8){(__bf16)(w0.x * scale), (__bf16)(w0.y * scale),
                                  (__bf16)(w0.z * scale), (__bf16)(w0.w * scale),
                                  (__bf16)(w1.x * scale), (__bf16)(w1.y * scale),
                                  (__bf16)(w1.z * scale), (__bf16)(w1.w * scale)};
        }
    __syncthreads();

#pragma unroll
    for (int ns = 0; ns < 2; ++ns) {
        const int nloc = w * 32 + ns * 16 + lr;
        bf16x8 bb0 = *(const bf16x8*)&xls[nloc][8 * lg];
        bf16x8 bb1 = *(const bf16x8*)&xls[nloc][32 + 8 * lg];
        f32x4 acc[4];
#pragma unroll
        for (int cot = 0; cot < 4; ++cot) acc[cot] = (f32x4){0.f, 0.f, 0.f, 0.f};
#pragma unroll
        for (int cot = 0; cot < 4; ++cot) {
            acc[cot] = __builtin_amdgcn_mfma_f32_16x16x32_bf16(a[cot][0], bb0, acc[cot], 0, 0, 0);
            acc[cot] = __builtin_amdgcn_mfma_f32_16x16x32_bf16(a[cot][1], bb1, acc[cot], 0, 0, 0);
        }
        // D lane: [co = cot*16 + 4lg + r][n = nloc] -> Qt[n][c] bf16x4
        __bf16* qp = Qt + (size_t)b * N_ * 64 + (size_t)(n0 + nloc) * 64;
#pragma unroll
        for (int cot = 0; cot < 4; ++cot) {
            bf16x4 ov = {(__bf16)acc[cot][0], (__bf16)acc[cot][1],
                         (__bf16)acc[cot][2], (__bf16)acc[cot][3]};
            *(bf16x4*)&qp[cot * 16 + 4 * lg] = ov;
        }
    }
}

// ---------------- K/V conv (2x2 s2) as MFMA: k=256 (4 taps x 64ci).
// Block: 64 m, all 64 co; blockIdx.z: 0=K -> Kt[m][c], 1=V -> Vh[c][m].
__global__ __launch_bounds__(256) void kvconv_mfma(const float* __restrict__ X,
                                                   const float* __restrict__ Wk,
                                                   const float* __restrict__ Wv,
                                                   __bf16* __restrict__ Kt,
                                                   __bf16* __restrict__ Vh) {
    __shared__ __bf16 xls[4][2][32][72];  // [p=row-2i0][dj][j][ci]
    __shared__ __bf16 Ws[4][64][72];      // [tap][co][ci]
    const int b = blockIdx.x, m0 = blockIdx.y * 64, kv = blockIdx.z;
    const int i0 = m0 >> 5;
    const int t = threadIdx.x, w = t >> 6, l = t & 63, lr = l & 15, lg = l >> 4;
    const float* Wsel = kv ? Wv : Wk;

    for (int idx = t; idx < 16384; idx += 256) {
        int co = idx >> 8, rem = idx & 255, ci = rem >> 2, tap = rem & 3;
        Ws[tap][co][ci] = (__bf16)Wsel[idx];
    }
    const float* Xb = X + (size_t)b * C_ * N_;
    for (int idx = t; idx < 4096; idx += 256) {          // 4p x 64c x 64ci floats
        int ci = idx >> 6, rem = idx & 63, p = rem >> 4, c4 = (rem & 15) * 4;
        float4 v = *(const float4*)&Xb[ci * N_ + (2 * i0 + p) * 64 + c4];
        xls[p][0][(c4 >> 1) + 0][ci] = (__bf16)v.x;
        xls[p][1][(c4 >> 1) + 0][ci] = (__bf16)v.y;
        xls[p][0][(c4 >> 1) + 1][ci] = (__bf16)v.z;
        xls[p][1][(c4 >> 1) + 1][ci] = (__bf16)v.w;
    }
    __syncthreads();

    const int iw = w >> 1, jw = (w & 1) * 16;
    f32x4 acc[4];
#pragma unroll
    for (int cot = 0; cot < 4; ++cot) acc[cot] = (f32x4){0.f, 0.f, 0.f, 0.f};
#pragma unroll
    for (int tap = 0; tap < 4; ++tap) {
        const int di = tap >> 1, dj = tap & 1;
#pragma unroll
        for (int ks = 0; ks < 2; ++ks) {
            bf16x8 bb = *(const bf16x8*)&xls[2 * iw + di][dj][jw + lr][ks * 32 + 8 * lg];
#pragma unroll
            for (int cot = 0; cot < 4; ++cot) {
                bf16x8 aa = *(const bf16x8*)&Ws[tap][cot * 16 + lr][ks * 32 + 8 * lg];
                acc[cot] = __builtin_amdgcn_mfma_f32_16x16x32_bf16(aa, bb, acc[cot], 0, 0, 0);
            }
        }
    }
    const int m = m0 + iw * 32 + jw + lr;
    if (kv == 0) {
        __bf16* kp = Kt + (size_t)b * NKV_ * 64 + (size_t)m * 64;
#pragma unroll
        for (int cot = 0; cot < 4; ++cot) {
            bf16x4 ov = {(__bf16)acc[cot][0], (__bf16)acc[cot][1],
                         (__bf16)acc[cot][2], (__bf16)acc[cot][3]};
            *(bf16x4*)&kp[cot * 16 + 4 * lg] = ov;
        }
    } else {
        __bf16* vp = Vh + (size_t)b * 64 * NKV_;
#pragma unroll
        for (int cot = 0; cot < 4; ++cot)
#pragma unroll
            for (int r = 0; r < 4; ++r)
                vp[(size_t)(cot * 16 + 4 * lg + r) * NKV_ + m] = (__bf16)acc[cot][r];
    }
}

// ---------------- MFMA flash attention: swapped QK + swapped PV -> OT[n][c] bf16.
__global__ __launch_bounds__(256, 4) void attn_mfma(const __bf16* __restrict__ Qt,
                                                    const __bf16* __restrict__ Kt,
                                                    const __bf16* __restrict__ Vh,
                                                    __bf16* __restrict__ OT) {
    __shared__ __attribute__((aligned(16))) __bf16 Pls[4][2][16][40];  // [wave][t][n][m+pad]
    const int bh = blockIdx.x;
    const int b = bh >> 1, h = bh & 1;
    const int w = threadIdx.x >> 6;
    const int l = threadIdx.x & 63;
    const int lr = l & 15, lg = l >> 4;
    const int nb = blockIdx.y * 128 + w * 32;

    const __bf16* Qb = Qt + (size_t)b * N_ * 64;
    const __bf16* Kb = Kt + (size_t)b * NKV_ * 64;
    const __bf16* Vb = Vh + (size_t)b * 64 * NKV_;

    bf16x8 qf0 = *(const bf16x8*)&Qb[(size_t)(nb + lr) * 64 + h * 32 + 8 * lg];
    bf16x8 qf1 = *(const bf16x8*)&Qb[(size_t)(nb + 16 + lr) * 64 + h * 32 + 8 * lg];
    const __bf16* Krow = Kb + (size_t)lr * 64 + h * 32 + 8 * lg;
    const __bf16* V0 = Vb + (size_t)(h * 32 + lr) * NKV_ + 8 * lg;
    const __bf16* V1 = V0 + (size_t)16 * NKV_;

    f32x4 oacc00 = {0,0,0,0}, oacc01 = {0,0,0,0}, oacc10 = {0,0,0,0}, oacc11 = {0,0,0,0};
    float lsum0 = 0.f, lsum1 = 0.f;

    bf16x8 kf0 = *(const bf16x8*)&Krow[0];
    bf16x8 kf1 = *(const bf16x8*)&Krow[(size_t)16 * 64];
    bf16x8 vf0 = *(const bf16x8*)&V0[0];
    bf16x8 vf1 = *(const bf16x8*)&V1[0];

    for (int mb = 0; mb < NKV_; mb += 32) {
        const int mn = (mb + 32) & (NKV_ - 1);
        bf16x8 nk0 = *(const bf16x8*)&Krow[(size_t)mn * 64];
        bf16x8 nk1 = *(const bf16x8*)&Krow[(size_t)(mn + 16) * 64];
        bf16x8 nv0 = *(const bf16x8*)&V0[mn];
        bf16x8 nv1 = *(const bf16x8*)&V1[mn];

        __builtin_amdgcn_s_setprio(1);
        f32x4 s00 = __builtin_amdgcn_mfma_f32_16x16x32_bf16(kf0, qf0, (f32x4){0,0,0,0}, 0, 0, 0);
        f32x4 s10 = __builtin_amdgcn_mfma_f32_16x16x32_bf16(kf1, qf0, (f32x4){0,0,0,0}, 0, 0, 0);
        f32x4 s01 = __builtin_amdgcn_mfma_f32_16x16x32_bf16(kf0, qf1, (f32x4){0,0,0,0}, 0, 0, 0);
        f32x4 s11 = __builtin_amdgcn_mfma_f32_16x16x32_bf16(kf1, qf1, (f32x4){0,0,0,0}, 0, 0, 0);
        __builtin_amdgcn_s_setprio(0);

        float p00[4], p10[4], p01[4], p11[4];
#pragma unroll
        for (int r = 0; r < 4; ++r) {
            p00[r] = __builtin_amdgcn_exp2f(s00[r]);
            p10[r] = __builtin_amdgcn_exp2f(s10[r]);
            p01[r] = __builtin_amdgcn_exp2f(s01[r]);
            p11[r] = __builtin_amdgcn_exp2f(s11[r]);
        }
        lsum0 += ((p00[0] + p00[1]) + (p00[2] + p00[3])) + ((p10[0] + p10[1]) + (p10[2] + p10[3]));
        lsum1 += ((p01[0] + p01[1]) + (p01[2] + p01[3])) + ((p11[0] + p11[1]) + (p11[2] + p11[3]));

        bf16x4 w00 = {(__bf16)p00[0], (__bf16)p00[1], (__bf16)p00[2], (__bf16)p00[3]};
        bf16x4 w10 = {(__bf16)p10[0], (__bf16)p10[1], (__bf16)p10[2], (__bf16)p10[3]};
        bf16x4 w01 = {(__bf16)p01[0], (__bf16)p01[1], (__bf16)p01[2], (__bf16)p01[3]};
        bf16x4 w11 = {(__bf16)p11[0], (__bf16)p11[1], (__bf16)p11[2], (__bf16)p11[3]};
        *(bf16x4*)&Pls[w][0][lr][4 * lg] = w00;
        *(bf16x4*)&Pls[w][0][lr][16 + 4 * lg] = w10;
        *(bf16x4*)&Pls[w][1][lr][4 * lg] = w01;
        *(bf16x4*)&Pls[w][1][lr][16 + 4 * lg] = w11;

        bf16x8 af0 = *(const bf16x8*)&Pls[w][0][lr][8 * lg];
        bf16x8 af1 = *(const bf16x8*)&Pls[w][1][lr][8 * lg];

        // PV swapped: D = mfma(V, P): rows = d, cols = n -> OT layout
        __builtin_amdgcn_s_setprio(1);
        oacc00 = __builtin_amdgcn_mfma_f32_16x16x32_bf16(vf0, af0, oacc00, 0, 0, 0);
        oacc01 = __builtin_amdgcn_mfma_f32_16x16x32_bf16(vf1, af0, oacc01, 0, 0, 0);
        oacc10 = __builtin_amdgcn_mfma_f32_16x16x32_bf16(vf0, af1, oacc10, 0, 0, 0);
        oacc11 = __builtin_amdgcn_mfma_f32_16x16x32_bf16(vf1, af1, oacc11, 0, 0, 0);
        __builtin_amdgcn_s_setprio(0);

        kf0 = nk0; kf1 = nk1; vf0 = nv0; vf1 = nv1;
    }

    // full row sums for n = lr (combine 4 lg-groups)
    lsum0 += __shfl_xor(lsum0, 16, 64);
    lsum0 += __shfl_xor(lsum0, 32, 64);
    lsum1 += __shfl_xor(lsum1, 16, 64);
    lsum1 += __shfl_xor(lsum1, 32, 64);
    const float inv0 = 1.0f / lsum0;
    const float inv1 = 1.0f / lsum1;

    // lane holds OT values: oaccXY[r] = O[d = Y*16 + 4lg + r][n = nb + X*16 + lr]
    __bf16* ob = OT + (size_t)b * N_ * 64;
    bf16x4 s;
    s = (bf16x4){(__bf16)(oacc00[0]*inv0), (__bf16)(oacc00[1]*inv0),
                 (__bf16)(oacc00[2]*inv0), (__bf16)(oacc00[3]*inv0)};
    *(bf16x4*)&ob[(size_t)(nb + lr) * 64 + h * 32 + 4 * lg] = s;
    s = (bf16x4){(__bf16)(oacc01[0]*inv0), (__bf16)(oacc01[1]*inv0),
                 (__bf16)(oacc01[2]*inv0), (__bf16)(oacc01[3]*inv0)};
    *(bf16x4*)&ob[(size_t)(nb + lr) * 64 + h * 32 + 16 + 4 * lg] = s;
    s = (bf16x4){(__bf16)(oacc10[0]*inv1), (__bf16)(oacc10[1]*inv1),
                 (__bf16)(oacc10[2]*inv1), (__bf16)(oacc10[3]*inv1)};
    *(bf16x4*)&ob[(size_t)(nb + 16 + lr) * 64 + h * 32 + 4 * lg] = s;
    s = (bf16x4){(__bf16)(oacc11[0]*inv1), (__bf16)(oacc11[1]*inv1),
                 (__bf16)(oacc11[2]*inv1), (__bf16)(oacc11[3]*inv1)};
    *(bf16x4*)&ob[(size_t)(nb + 16 + lr) * 64 + h * 32 + 16 + 4 * lg] = s;
}

// ---------------- proj (1x1) as MFMA: B-frags straight from OT (global), out fp32.
__global__ __launch_bounds__(256) void proj_mfma(const __bf16* __restrict__ OT,
                                                 const float* __restrict__ W,
                                                 float* __restrict__ out) {
    const int b = blockIdx.x, n0 = blockIdx.y * 128, t = threadIdx.x;
    const int w = t >> 6, l = t & 63, lr = l & 15, lg = l >> 4;

    bf16x8 a[4][2];
#pragma unroll
    for (int cot = 0; cot < 4; ++cot)
#pragma unroll
        for (int ks = 0; ks < 2; ++ks) {
            const float* wp = &W[(cot * 16 + lr) * 64 + ks * 32 + 8 * lg];
            float4 w0 = *(const float4*)wp;
            float4 w1 = *(const float4*)(wp + 4);
            a[cot][ks] = (bf16x8){(__bf16)w0.x, (__bf16)w0.y, (__bf16)w0.z, (__bf16)w0.w,
                                  (__bf16)w1.x, (__bf16)w1.y, (__bf16)w1.z, (__bf16)w1.w};
        }

#pragma unroll
    for (int ns = 0; ns < 2; ++ns) {
        const int n_g = n0 + w * 32 + ns * 16 + lr;
        const __bf16* op = OT + (size_t)b * N_ * 64 + (size_t)n_g * 64;
        bf16x8 bb0 = *(const bf16x8*)&op[8 * lg];
        bf16x8 bb1 = *(const bf16x8*)&op[32 + 8 * lg];
        f32x4 acc[4];
#pragma unroll
        for (int cot = 0; cot < 4; ++cot) acc[cot] = (f32x4){0.f, 0.f, 0.f, 0.f};
#pragma unroll
        for (int cot = 0; cot < 4; ++cot) {
            acc[cot] = __builtin_amdgcn_mfma_f32_16x16x32_bf16(a[cot][0], bb0, acc[cot], 0, 0, 0);
            acc[cot] = __builtin_amdgcn_mfma_f32_16x16x32_bf16(a[cot][1], bb1, acc[cot], 0, 0, 0);
        }
        float* yb = out + (size_t)b * C_ * N_ + n_g;
#pragma unroll
        for (int cot = 0; cot < 4; ++cot)
#pragma unroll
            for (int r = 0; r < 4; ++r)
                yb[(size_t)(cot * 16 + 4 * lg + r) * N_] = acc[cot][r];
    }
}

extern "C" void kernel_launch(void* const* d_in, const int* in_sizes, int n_in,
                              void* d_out, int out_size, void* d_ws, size_t ws_size,
                              hipStream_t stream) {
    const float* x     = (const float*)d_in[0];
    const float* wq    = (const float*)d_in[1];
    const float* wk    = (const float*)d_in[2];
    const float* wv    = (const float*)d_in[3];
    const float* wproj = (const float*)d_in[4];
    float* out = (float*)d_out;

    char* ws = (char*)d_ws;
    __bf16* Qt = (__bf16*)ws;                                   // 16*4096*64*2 = 8.39 MB
    __bf16* Kt = (__bf16*)(ws + 8388608);                       // 2.10 MB
    __bf16* Vh = (__bf16*)(ws + 8388608 + 2097152);             // 2.10 MB
    __bf16* OT = (__bf16*)(ws + 8388608 + 2097152 + 2097152);   // 8.39 MB

    qconv_mfma <<<dim3(B_, N_ / 128), 256, 0, stream>>>(x, wq, Qt);
    kvconv_mfma<<<dim3(B_, NKV_ / 64, 2), 256, 0, stream>>>(x, wk, wv, Kt, Vh);
    attn_mfma  <<<dim3(B_ * 2, N_ / 128), 256, 0, stream>>>(Qt, Kt, Vh, OT);
    proj_mfma  <<<dim3(B_, N_ / 128), 256, 0, stream>>>(OT, wproj, out);
}